// Round 2
// baseline (9165.775 us; speedup 1.0000x reference)
//
#include <hip/hip_runtime.h>
#include <hip/hip_bf16.h>

// LSTM DynamicRNN: B=128, T=512, D=256, H=512.
// Round 5 "wave-actor": zero __syncthreads. Each wave (ms,nt) of each block
// owns a 16-row x 4-unit output tile with ALL FOUR GATES as its 16 MFMA
// columns (col = gate*512 + jh0 + nt*4 + uu), so gates are computed after a
// wave-PRIVATE LDS transpose (lgkmcnt only). c-state in registers, x A-frags
// in registers (per-wave prefetch, vmcnt-counted), out[] stores issued in the
// next step's load shadow. Publication is per-wave flags[bt][ms][ct*2+nt];
// consumer wave ms polls only its ms-shard's 128 producer waves -> the grid
// decomposes into 8 independent dependency domains (2 bt x 4 ms).

#define B_   128
#define T_   512
#define D_   256
#define H_   512
#define G4_  2048   // 4*H
#define NBLK 128
#define HREC (64 * 128 * 8)   // shorts per parity plane of hbuf

typedef __attribute__((ext_vector_type(8))) short short8;
typedef __attribute__((ext_vector_type(4))) float float4v;
typedef __attribute__((ext_vector_type(4))) int   int4v;

__device__ inline unsigned short f2bf_bits(float f) {
    union { float f; unsigned u; } v; v.f = f;
    unsigned r = (v.u + 0x7FFFu + ((v.u >> 16) & 1u)) >> 16;
    return (unsigned short)r;
}

__device__ inline float sigmoid_fast(float x) {
    return 1.f / (1.f + __expf(-x));
}

__device__ inline float tanh_fast(float x) {
    float a = fabsf(x);
    float e = __expf(-2.f * a);
    float r = (1.f - e) / (1.f + e);
    return copysignf(r, x);
}

union HAu { int4v i4; short8 s8; };

__global__ __launch_bounds__(512, 2) void lstm_wave(
    const float* __restrict__ x, const float* __restrict__ Wx,
    const float* __restrict__ Wh, const float* __restrict__ bias,
    float* __restrict__ out, unsigned short* __restrict__ hbuf,
    unsigned int* __restrict__ flags)
{
    const int tid  = threadIdx.x;
    const int lane = tid & 63;
    const int wave = tid >> 6;      // 8 waves
    const int ms   = wave & 3;      // batch strip (16 rows) within 64-row tile
    const int nt   = wave >> 2;     // unit half: units nt*4..+3 of this block
    const int ct   = blockIdx.x & 63;   // hidden-unit tile: units ct*8..+7
    const int bt   = blockIdx.x >> 6;   // batch tile: rows bt*64..+63
    const int jh0  = ct * 8;
    const int l15  = lane & 15;
    const int l4   = lane >> 4;

    __shared__ float zls[8][16 * 20];   // wave-private transpose tiles

    // consumer A-frag rows (own ms strip)
    const int mrow = ms * 16 + l15;
    const int gb_a = bt * 64 + mrow;

    // target (gate-phase) mapping: one (row,unit) per lane
    const int row_t  = lane >> 2;       // 0..15
    const int uu_t   = lane & 3;        // 0..3
    const int unit_t = jh0 + nt * 4 + uu_t;
    const int gb_t   = bt * 64 + ms * 16 + row_t;

    // ---- register-resident weight B-frags, gate-interleaved columns ----
    // ncol = l15 = gate*4 + uu  ->  global col = gate*512 + jh0 + nt*4 + uu
    const int wcol = (l15 >> 2) * 512 + jh0 + nt * 4 + (l15 & 3);
    short8 wfrag[24];                   // ks 0..7 = Wx, 8..23 = Wh
#pragma unroll
    for (int ks = 0; ks < 24; ++ks) {
        short8 w;
#pragma unroll
        for (int j = 0; j < 8; ++j) {
            int k = ks * 32 + l4 * 8 + j;
            float v = (k < D_) ? Wx[(size_t)k * G4_ + wcol]
                               : Wh[(size_t)(k - D_) * G4_ + wcol];
            w[j] = (short)f2bf_bits(v);
        }
        wfrag[ks] = w;
    }

    const float bq0 = bias[0 * 512 + unit_t];
    const float bq1 = bias[1 * 512 + unit_t];
    const float bq2 = bias[2 * 512 + unit_t];
    const float bq3 = bias[3 * 512 + unit_t];

    // per-lane x source: row mrow, chunk base includes l4*8
    const float* const xlane = x + (size_t)gb_a * (T_ * D_) + l4 * 8;

    // ---- prologue: issue + drain x_0 loads ----
    float4v xf[16];
    {
        const float* xp = xlane;        // t = 0
#pragma unroll
        for (int ks = 0; ks < 8; ++ks) {
            asm volatile("global_load_dwordx4 %0, %1, off"
                         : "=v"(xf[2 * ks])     : "v"(xp + ks * 32));
            asm volatile("global_load_dwordx4 %0, %1, off"
                         : "=v"(xf[2 * ks + 1]) : "v"(xp + ks * 32 + 4));
        }
        asm volatile("s_waitcnt vmcnt(0)" ::: "memory");
        __builtin_amdgcn_sched_barrier(0);
    }

    unsigned int* const fshard = flags + bt * 512 + ms * 128;  // this ms-shard
    unsigned int* const fpoll  = fshard + lane * 2;
    unsigned int* const fpub   = fshard + ct * 2 + nt;

    const unsigned short* const hb00 = hbuf + ((size_t)l4 * 128 + gb_a) * 8;
    unsigned short* const hst0 = hbuf + ((size_t)ct * 128 + gb_t) * 8 + nt * 4 + uu_t;
    float* const op = out + (size_t)gb_t * (T_ * H_) + unit_t;

    float c_reg = 0.f, h_prev = 0.f;

    for (int t = 0; t < T_; ++t) {
        // ---- (1) pack x_t A-frags (xf drained by previous vmcnt(0)) ----
        short8 xfrag[8];
#pragma unroll
        for (int ks = 0; ks < 8; ++ks) {
            short8 g;
            g[0] = (short)f2bf_bits(xf[2 * ks][0]);
            g[1] = (short)f2bf_bits(xf[2 * ks][1]);
            g[2] = (short)f2bf_bits(xf[2 * ks][2]);
            g[3] = (short)f2bf_bits(xf[2 * ks][3]);
            g[4] = (short)f2bf_bits(xf[2 * ks + 1][0]);
            g[5] = (short)f2bf_bits(xf[2 * ks + 1][1]);
            g[6] = (short)f2bf_bits(xf[2 * ks + 1][2]);
            g[7] = (short)f2bf_bits(xf[2 * ks + 1][3]);
            xfrag[ks] = g;
        }

        // ---- (2) poll own ms-shard: 128 producer waves at step >= t ----
        if (t) {
            const unsigned tgt = (unsigned)t;
            while (true) {
                unsigned f0 = __hip_atomic_load(fpoll,     __ATOMIC_RELAXED,
                                                __HIP_MEMORY_SCOPE_AGENT);
                unsigned f1 = __hip_atomic_load(fpoll + 1, __ATOMIC_RELAXED,
                                                __HIP_MEMORY_SCOPE_AGENT);
                if (__all((int)(f0 >= tgt && f1 >= tgt))) break;
            }
        }

        // ---- (3) shadow out-store of row t-1 (oldest in vmem stream) ----
        if (t) {
            const float* opt = op + (size_t)(t - 1) * H_;
            asm volatile("global_store_dword %0, %1, off"
                         :: "v"(opt), "v"(h_prev) : "memory");
        }

        // ---- (4) coherent h_t loads: 16 x dwordx4 ----
        HAu ha[16];
        {
            const unsigned short* hb0 = hb00 + (size_t)(t & 1) * HREC;
#pragma unroll
            for (int ks = 0; ks < 16; ++ks) {
                const unsigned short* ap = hb0 + (size_t)ks * (4 * 128 * 8);
                asm volatile("global_load_dwordx4 %0, %1, off sc0 sc1"
                             : "=v"(ha[ks].i4) : "v"(ap));
            }
        }

        // ---- (5) x-part MFMAs (overlap h-load latency) ----
        float4v acc = {0.f, 0.f, 0.f, 0.f};
#pragma unroll
        for (int ks = 0; ks < 8; ++ks)
            acc = __builtin_amdgcn_mfma_f32_16x16x32_bf16(
                      xfrag[ks], wfrag[ks], acc, 0, 0, 0);

        // ---- (6/7) h MFMAs phase 1 ----
        asm volatile("s_waitcnt vmcnt(8)" ::: "memory");
        __builtin_amdgcn_sched_barrier(0);
        __builtin_amdgcn_s_setprio(1);
#pragma unroll
        for (int ks = 0; ks < 8; ++ks)
            acc = __builtin_amdgcn_mfma_f32_16x16x32_bf16(
                      ha[ks].s8, wfrag[8 + ks], acc, 0, 0, 0);
        __builtin_amdgcn_s_setprio(0);

        // ---- (8) issue x_{t+1} loads, then wait out the h tail ----
        if (t + 1 < T_) {
            const float* xp = xlane + (size_t)(t + 1) * D_;
#pragma unroll
            for (int ks = 0; ks < 8; ++ks) {
                asm volatile("global_load_dwordx4 %0, %1, off"
                             : "=v"(xf[2 * ks])     : "v"(xp + ks * 32));
                asm volatile("global_load_dwordx4 %0, %1, off"
                             : "=v"(xf[2 * ks + 1]) : "v"(xp + ks * 32 + 4));
            }
            asm volatile("s_waitcnt vmcnt(16)" ::: "memory");
        } else {
            asm volatile("s_waitcnt vmcnt(0)" ::: "memory");
        }
        __builtin_amdgcn_sched_barrier(0);

        // ---- (9) h MFMAs phase 2 ----
        float4v accB = {0.f, 0.f, 0.f, 0.f};
        __builtin_amdgcn_s_setprio(1);
#pragma unroll
        for (int ks = 8; ks < 16; ++ks)
            accB = __builtin_amdgcn_mfma_f32_16x16x32_bf16(
                       ha[ks].s8, wfrag[8 + ks], accB, 0, 0, 0);
        __builtin_amdgcn_s_setprio(0);

        // ---- (10/11) wave-private LDS transpose ----
#pragma unroll
        for (int r = 0; r < 4; ++r)
            zls[wave][(l4 * 4 + r) * 20 + l15] = acc[r] + accB[r];
        asm volatile("s_waitcnt lgkmcnt(0)" ::: "memory");
        __builtin_amdgcn_sched_barrier(0);

        // ---- (12/13) gates (one (row,unit) per lane, all 4 gates) ----
        float zg0 = zls[wave][row_t * 20 + 0 + uu_t];
        float zg1 = zls[wave][row_t * 20 + 4 + uu_t];
        float zg2 = zls[wave][row_t * 20 + 8 + uu_t];
        float zg3 = zls[wave][row_t * 20 + 12 + uu_t];
        float ig = sigmoid_fast(zg0 + bq0);
        float fg = sigmoid_fast(zg1 + bq1);
        float gg = tanh_fast(zg2 + bq2);
        float og = sigmoid_fast(zg3 + bq3);
        c_reg = fg * c_reg + ig * gg;
        float hnew = og * tanh_fast(c_reg);

        // ---- (14) publish h_{t+1}: store -> ack -> per-wave flag ----
        if (t + 1 < T_) {
            unsigned hv = (unsigned)f2bf_bits(hnew);
            unsigned short* hp = hst0 + (size_t)((t + 1) & 1) * HREC;
            asm volatile("global_store_short %0, %1, off sc0 sc1"
                         :: "v"(hp), "v"(hv) : "memory");
            asm volatile("s_waitcnt vmcnt(0)" ::: "memory");
            __builtin_amdgcn_sched_barrier(0);
            if (lane == 0)
                __hip_atomic_store(fpub, (unsigned)(t + 1), __ATOMIC_RELAXED,
                                   __HIP_MEMORY_SCOPE_AGENT);
        }
        h_prev = hnew;
    }

    // ---- epilogue: last output row + final states ----
    const size_t BTH = (size_t)B_ * T_ * H_;
    op[(size_t)(T_ - 1) * H_] = h_prev;
    out[BTH + (size_t)gb_t * H_ + unit_t] = h_prev;
    out[BTH + (size_t)B_ * H_ + (size_t)gb_t * H_ + unit_t] = c_reg;
}

extern "C" void kernel_launch(void* const* d_in, const int* in_sizes, int n_in,
                              void* d_out, int out_size, void* d_ws, size_t ws_size,
                              hipStream_t stream) {
    const float* x    = (const float*)d_in[0];
    const float* Wx   = (const float*)d_in[1];
    const float* Wh   = (const float*)d_in[2];
    const float* bias = (const float*)d_in[3];
    float* out = (float*)d_out;

    unsigned short* hbuf = (unsigned short*)d_ws;  // 2x[64][128][8] bf16
    const size_t hbuf_bytes = (size_t)2 * 64 * 128 * 8 * sizeof(unsigned short);
    unsigned int* flags = (unsigned int*)((char*)d_ws + hbuf_bytes);  // [2][4][128]

    hipMemsetAsync(d_ws, 0, hbuf_bytes + 4096, stream);

    lstm_wave<<<dim3(NBLK), dim3(512), 0, stream>>>(
        x, Wx, Wh, bias, out, hbuf, flags);
}

// Round 3
// 3988.490 us; speedup vs baseline: 2.2981x; 2.2981x over previous
//
#include <hip/hip_runtime.h>
#include <hip/hip_bf16.h>

// LSTM DynamicRNN: B=128, T=512, D=256, H=512.
// Round 6 "wave-actor repaired": 256 blocks x 256 threads (4 waves) -> one
// block per CU, 1 wave/SIMD, __launch_bounds__(256,1) raises the register
// cap so the full working set (wfrag 96 + xf 64 + ha 64 + xfrag 32) lives in
// registers -- Round 5's fatal spill storm is gone. Zero __syncthreads:
// each wave owns a 16-row x 4-unit tile with all four gates as its 16 MFMA
// columns; gates via wave-private LDS transpose (lgkmcnt only). Per-wave
// flags in closed (bt,ms) shards. vmcnt ordering fixed: x_{t+1} loads are
// issued AFTER the flag publish (so the publish-ack vmcnt(0) covers only
// the h-store), and the out[] store is issued first after poll-detect so
// it is long-acked by the phase-2 vmcnt(0).

#define B_   128
#define T_   512
#define D_   256
#define H_   512
#define G4_  2048   // 4*H
#define NBLK 256
#define HREC (64 * 128 * 8)   // shorts per parity plane of hbuf

typedef __attribute__((ext_vector_type(8))) short short8;
typedef __attribute__((ext_vector_type(4))) float float4v;
typedef __attribute__((ext_vector_type(4))) int   int4v;

__device__ inline unsigned short f2bf_bits(float f) {
    union { float f; unsigned u; } v; v.f = f;
    unsigned r = (v.u + 0x7FFFu + ((v.u >> 16) & 1u)) >> 16;
    return (unsigned short)r;
}

__device__ inline float sigmoid_fast(float x) {
    return 1.f / (1.f + __expf(-x));
}

__device__ inline float tanh_fast(float x) {
    float a = fabsf(x);
    float e = __expf(-2.f * a);
    float r = (1.f - e) / (1.f + e);
    return copysignf(r, x);
}

union HAu { int4v i4; short8 s8; };

__global__ __launch_bounds__(256, 1) void lstm_wave(
    const float* __restrict__ x, const float* __restrict__ Wx,
    const float* __restrict__ Wh, const float* __restrict__ bias,
    float* __restrict__ out, unsigned short* __restrict__ hbuf,
    unsigned int* __restrict__ flags)
{
    const int tid  = threadIdx.x;
    const int lane = tid & 63;
    const int wave = tid >> 6;          // 0..3
    const int bid  = blockIdx.x;        // 0..255
    const int ct   = bid & 63;          // hidden-unit tile: units ct*8..+7
    const int grp  = bid >> 6;          // 0..3
    const int bt   = grp >> 1;          // batch tile: rows bt*64..+63
    const int ms   = (grp & 1) * 2 + (wave & 1);  // batch strip (16 rows)
    const int nt   = wave >> 1;         // unit half: units nt*4..+3
    const int jh0  = ct * 8;
    const int l15  = lane & 15;
    const int l4   = lane >> 4;

    __shared__ float zls[4][16 * 20];   // wave-private transpose tiles

    // consumer A-frag rows (own ms strip)
    const int mrow = ms * 16 + l15;
    const int gb_a = bt * 64 + mrow;

    // target (gate-phase) mapping: one (row,unit) per lane
    const int row_t  = lane >> 2;       // 0..15
    const int uu_t   = lane & 3;        // 0..3
    const int unit_t = jh0 + nt * 4 + uu_t;
    const int gb_t   = bt * 64 + ms * 16 + row_t;

    // ---- register-resident weight B-frags, gate-interleaved columns ----
    // ncol = l15 = gate*4 + uu  ->  global col = gate*512 + jh0 + nt*4 + uu
    const int wcol = (l15 >> 2) * 512 + jh0 + nt * 4 + (l15 & 3);
    short8 wfrag[24];                   // ks 0..7 = Wx, 8..23 = Wh
#pragma unroll
    for (int ks = 0; ks < 24; ++ks) {
        short8 w;
#pragma unroll
        for (int j = 0; j < 8; ++j) {
            int k = ks * 32 + l4 * 8 + j;
            float v = (k < D_) ? Wx[(size_t)k * G4_ + wcol]
                               : Wh[(size_t)(k - D_) * G4_ + wcol];
            w[j] = (short)f2bf_bits(v);
        }
        wfrag[ks] = w;
    }

    const float bq0 = bias[0 * 512 + unit_t];
    const float bq1 = bias[1 * 512 + unit_t];
    const float bq2 = bias[2 * 512 + unit_t];
    const float bq3 = bias[3 * 512 + unit_t];

    // per-lane x source: row mrow, chunk base includes l4*8
    const float* const xlane = x + (size_t)gb_a * (T_ * D_) + l4 * 8;

    // ---- prologue: issue x_0 loads (drained at loop top) ----
    float4v xf[16];
    {
        const float* xp = xlane;        // t = 0
#pragma unroll
        for (int ks = 0; ks < 8; ++ks) {
            asm volatile("global_load_dwordx4 %0, %1, off"
                         : "=v"(xf[2 * ks])     : "v"(xp + ks * 32));
            asm volatile("global_load_dwordx4 %0, %1, off"
                         : "=v"(xf[2 * ks + 1]) : "v"(xp + ks * 32 + 4));
        }
    }

    unsigned int* const fshard = flags + bt * 512 + ms * 128;  // this shard
    unsigned int* const fpoll  = fshard + lane * 2;
    unsigned int* const fpub   = fshard + ct * 2 + nt;

    const unsigned short* const hb00 = hbuf + ((size_t)l4 * 128 + gb_a) * 8;
    unsigned short* const hst0 = hbuf + ((size_t)ct * 128 + gb_t) * 8 + nt * 4 + uu_t;
    float* const op = out + (size_t)gb_t * (T_ * H_) + unit_t;

    float c_reg = 0.f, h_prev = 0.f;

    for (int t = 0; t < T_; ++t) {
        // ---- (1) poll own ms-shard: 128 producer waves at step >= t ----
        if (t) {
            const unsigned tgt = (unsigned)t;
            while (true) {
                unsigned f0 = __hip_atomic_load(fpoll,     __ATOMIC_RELAXED,
                                                __HIP_MEMORY_SCOPE_AGENT);
                unsigned f1 = __hip_atomic_load(fpoll + 1, __ATOMIC_RELAXED,
                                                __HIP_MEMORY_SCOPE_AGENT);
                if (__all((int)(f0 >= tgt && f1 >= tgt))) break;
            }
        }

        // ---- (2) drain x_t loads, pack A-frags ----
        asm volatile("s_waitcnt vmcnt(0)" ::: "memory");
        __builtin_amdgcn_sched_barrier(0);
        short8 xfrag[8];
#pragma unroll
        for (int ks = 0; ks < 8; ++ks) {
            short8 g;
            g[0] = (short)f2bf_bits(xf[2 * ks][0]);
            g[1] = (short)f2bf_bits(xf[2 * ks][1]);
            g[2] = (short)f2bf_bits(xf[2 * ks][2]);
            g[3] = (short)f2bf_bits(xf[2 * ks][3]);
            g[4] = (short)f2bf_bits(xf[2 * ks + 1][0]);
            g[5] = (short)f2bf_bits(xf[2 * ks + 1][1]);
            g[6] = (short)f2bf_bits(xf[2 * ks + 1][2]);
            g[7] = (short)f2bf_bits(xf[2 * ks + 1][3]);
            xfrag[ks] = g;
        }

        // ---- (3) shadow out-store of row t-1 (oldest in vmem stream,
        //          plain store: acks at L2 well before phase-2 vmcnt(0)) ----
        if (t) {
            const float* opt = op + (size_t)(t - 1) * H_;
            asm volatile("global_store_dword %0, %1, off"
                         :: "v"(opt), "v"(h_prev) : "memory");
        }

        // ---- (4) coherent h_t loads: 16 x dwordx4 ----
        HAu ha[16];
        {
            const unsigned short* hb0 = hb00 + (size_t)(t & 1) * HREC;
#pragma unroll
            for (int ks = 0; ks < 16; ++ks) {
                const unsigned short* ap = hb0 + (size_t)ks * (4 * 128 * 8);
                asm volatile("global_load_dwordx4 %0, %1, off sc0 sc1"
                             : "=v"(ha[ks].i4) : "v"(ap));
            }
        }

        // ---- (5) x-part MFMAs (overlap h-load latency) ----
        float4v acc = {0.f, 0.f, 0.f, 0.f};
#pragma unroll
        for (int ks = 0; ks < 8; ++ks)
            acc = __builtin_amdgcn_mfma_f32_16x16x32_bf16(
                      xfrag[ks], wfrag[ks], acc, 0, 0, 0);

        // ---- (6) h MFMAs phase 1 (out-store is oldest: 17 outstanding,
        //          first 8 h-loads done when <=8 remain) ----
        asm volatile("s_waitcnt vmcnt(8)" ::: "memory");
        __builtin_amdgcn_sched_barrier(0);
        __builtin_amdgcn_s_setprio(1);
#pragma unroll
        for (int ks = 0; ks < 8; ++ks)
            acc = __builtin_amdgcn_mfma_f32_16x16x32_bf16(
                      ha[ks].s8, wfrag[8 + ks], acc, 0, 0, 0);
        __builtin_amdgcn_s_setprio(0);

        // ---- (7) h MFMAs phase 2 ----
        asm volatile("s_waitcnt vmcnt(0)" ::: "memory");
        __builtin_amdgcn_sched_barrier(0);
        float4v accB = {0.f, 0.f, 0.f, 0.f};
        __builtin_amdgcn_s_setprio(1);
#pragma unroll
        for (int ks = 8; ks < 16; ++ks)
            accB = __builtin_amdgcn_mfma_f32_16x16x32_bf16(
                       ha[ks].s8, wfrag[8 + ks], accB, 0, 0, 0);
        __builtin_amdgcn_s_setprio(0);

        // ---- (8) wave-private LDS transpose ----
#pragma unroll
        for (int r = 0; r < 4; ++r)
            zls[wave][(l4 * 4 + r) * 20 + l15] = acc[r] + accB[r];
        asm volatile("s_waitcnt lgkmcnt(0)" ::: "memory");
        __builtin_amdgcn_sched_barrier(0);

        // ---- (9) gates (one (row,unit) per lane, all 4 gates) ----
        float zg0 = zls[wave][row_t * 20 + 0 + uu_t];
        float zg1 = zls[wave][row_t * 20 + 4 + uu_t];
        float zg2 = zls[wave][row_t * 20 + 8 + uu_t];
        float zg3 = zls[wave][row_t * 20 + 12 + uu_t];
        float ig = sigmoid_fast(zg0 + bq0);
        float fg = sigmoid_fast(zg1 + bq1);
        float gg = tanh_fast(zg2 + bq2);
        float og = sigmoid_fast(zg3 + bq3);
        c_reg = fg * c_reg + ig * gg;
        float hnew = og * tanh_fast(c_reg);

        // ---- (10) publish h_{t+1}: store -> ack -> per-wave flag ----
        if (t + 1 < T_) {
            unsigned hv = (unsigned)f2bf_bits(hnew);
            unsigned short* hp = hst0 + (size_t)((t + 1) & 1) * HREC;
            asm volatile("global_store_short %0, %1, off sc0 sc1"
                         :: "v"(hp), "v"(hv) : "memory");
            asm volatile("s_waitcnt vmcnt(0)" ::: "memory");
            __builtin_amdgcn_sched_barrier(0);
            if (lane == 0)
                __hip_atomic_store(fpub, (unsigned)(t + 1), __ATOMIC_RELAXED,
                                   __HIP_MEMORY_SCOPE_AGENT);
            __builtin_amdgcn_sched_barrier(0);

            // ---- (11) issue x_{t+1} loads (drained at next loop top) ----
            const float* xp = xlane + (size_t)(t + 1) * D_;
#pragma unroll
            for (int ks = 0; ks < 8; ++ks) {
                asm volatile("global_load_dwordx4 %0, %1, off"
                             : "=v"(xf[2 * ks])     : "v"(xp + ks * 32));
                asm volatile("global_load_dwordx4 %0, %1, off"
                             : "=v"(xf[2 * ks + 1]) : "v"(xp + ks * 32 + 4));
            }
        }
        h_prev = hnew;
    }

    // ---- epilogue: last output row + final states ----
    const size_t BTH = (size_t)B_ * T_ * H_;
    op[(size_t)(T_ - 1) * H_] = h_prev;
    out[BTH + (size_t)gb_t * H_ + unit_t] = h_prev;
    out[BTH + (size_t)B_ * H_ + (size_t)gb_t * H_ + unit_t] = c_reg;
}

extern "C" void kernel_launch(void* const* d_in, const int* in_sizes, int n_in,
                              void* d_out, int out_size, void* d_ws, size_t ws_size,
                              hipStream_t stream) {
    const float* x    = (const float*)d_in[0];
    const float* Wx   = (const float*)d_in[1];
    const float* Wh   = (const float*)d_in[2];
    const float* bias = (const float*)d_in[3];
    float* out = (float*)d_out;

    unsigned short* hbuf = (unsigned short*)d_ws;  // 2x[64][128][8] bf16
    const size_t hbuf_bytes = (size_t)2 * 64 * 128 * 8 * sizeof(unsigned short);
    unsigned int* flags = (unsigned int*)((char*)d_ws + hbuf_bytes);  // [2][4][128]

    hipMemsetAsync(d_ws, 0, hbuf_bytes + 4096, stream);

    lstm_wave<<<dim3(NBLK), dim3(256), 0, stream>>>(
        x, Wx, Wh, bias, out, hbuf, flags);
}